// Round 5
// baseline (24184.961 us; speedup 1.0000x reference)
//
#include <hip/hip_runtime.h>
#include <hip/hip_bf16.h>

#define BATCH 64
#define SEQ   2048
#define DIN   64
#define HID   256
#define NCLS  8

__device__ __forceinline__ float sigm(float x)  { return 1.0f / (1.0f + __expf(-x)); }
__device__ __forceinline__ float tanh_f(float x){ return 1.0f - 2.0f / (__expf(2.0f * x) + 1.0f); }

// out[b][t][c] = bfc[c]; FC overwrites t < len, so t >= len keeps exactly bfc.
__global__ void init_out_kernel(float* __restrict__ out, const float* __restrict__ bfc) {
    int idx = blockIdx.x * blockDim.x + threadIdx.x;
    if (idx < BATCH * SEQ * NCLS) out[idx] = bfc[idx & 7];
}

// ---------------------------------------------------------------------------
// L0: 256 blocks = mem(8) x pair(32). Block (mem,P) serves batches {2P,2P+1};
// owns 128 gate rows: row = gate*256 + mem*32 + k, k<32. Weights 128x320 =
// 40 fp32/thread -> fits the allocator's hard 64-VGPR budget (rounds 1-4:
// VGPR_Count pinned at 64; w[80] => remat/spill). Members stride 32 == 0 mod 8
// -> all 8 members of a pair share one XCD (h-exchange stays in that L2).
// ---------------------------------------------------------------------------
__global__ void lstm_l0_kernel(
    const float* __restrict__ x,    const float* __restrict__ Wih0,
    const float* __restrict__ Whh0, const float* __restrict__ bih0,
    const float* __restrict__ bhh0, float* __restrict__ hist,
    int* __restrict__ flagsA)
{
    const int P   = blockIdx.x & 31;
    const int mem = blockIdx.x >> 5;       // 0..7
    const int tid = threadIdx.x;
    const int p   = tid >> 7;              // 0..7 col-chunk (40 wide)
    const int r   = tid & 127;             // 0..127 local row
    const int row = (r >> 5) * 256 + mem * 32 + (r & 31);

    float w[40];
#pragma unroll
    for (int q = 0; q < 40; ++q) {
        int col = p * 40 + q;
        w[q] = (col < DIN) ? Wih0[row * DIN + col] : Whh0[row * HID + (col - DIN)];
    }
#pragma unroll
    for (int q = 0; q < 40; ++q) asm volatile("" : "+v"(w[q]));  // keep resident

    float biasv = 0.f;
    if (tid < 256) {
        int rr = tid & 127;
        int row2 = (rr >> 5) * 256 + mem * 32 + (rr & 31);
        biasv = bih0[row2] + bhh0[row2];
    }
    asm volatile("" : "+v"(biasv));
    float creg = 0.f;                      // tid<64: c for (n=tid>>5, k=tid&31)

    __shared__ __align__(16) float v[640]; // [n][ x(64) | h1_prev(256) ]
    __shared__ float pbuf[2048];           // [n][p][r]
    __shared__ float act[256];             // [n][128]

    for (int t = 0; t < SEQ; ++t) {
        if (t > 0 && tid < 8) {
            while (__hip_atomic_load(&flagsA[P * 8 + tid], __ATOMIC_ACQUIRE,
                                     __HIP_MEMORY_SCOPE_AGENT) < t) {}
        }
        __syncthreads();
        if (tid < 640) {
            int n = (tid >= 320) ? 1 : 0;
            int j = tid - n * 320;
            int b = 2 * P + n;
            float val;
            if (j < DIN) {
                val = x[((size_t)b * SEQ + t) * DIN + j];
            } else {
                val = (t == 0) ? 0.f
                    : __hip_atomic_load(&hist[((size_t)(t - 1) * BATCH + b) * HID + (j - DIN)],
                                        __ATOMIC_RELAXED, __HIP_MEMORY_SCOPE_AGENT);
            }
            v[n * 320 + j] = val;
        }
        __syncthreads();

        float a0 = 0.f, a1 = 0.f;
#pragma unroll
        for (int qq = 0; qq < 10; ++qq) {
            float4 va = *(const float4*)&v[p * 40 + qq * 4];        // wave-uniform bcast
            a0 = fmaf(w[qq * 4 + 0], va.x, a0);
            a0 = fmaf(w[qq * 4 + 1], va.y, a0);
            a0 = fmaf(w[qq * 4 + 2], va.z, a0);
            a0 = fmaf(w[qq * 4 + 3], va.w, a0);
            float4 vb = *(const float4*)&v[320 + p * 40 + qq * 4];
            a1 = fmaf(w[qq * 4 + 0], vb.x, a1);
            a1 = fmaf(w[qq * 4 + 1], vb.y, a1);
            a1 = fmaf(w[qq * 4 + 2], vb.z, a1);
            a1 = fmaf(w[qq * 4 + 3], vb.w, a1);
        }
        pbuf[p * 128 + r]        = a0;
        pbuf[1024 + p * 128 + r] = a1;
        __syncthreads();

        if (tid < 256) {
            int n = tid >> 7, rr = tid & 127;
            float s = biasv;
#pragma unroll
            for (int q = 0; q < 8; ++q) s += pbuf[n * 1024 + q * 128 + rr];
            act[n * 128 + rr] = ((rr >> 5) == 2) ? tanh_f(s) : sigm(s);
        }
        __syncthreads();

        if (tid < 64) {
            int n = tid >> 5, k = tid & 31, b = 2 * P + n;
            float iv = act[n * 128 + k],      fv = act[n * 128 + 32 + k];
            float gv = act[n * 128 + 64 + k], ov = act[n * 128 + 96 + k];
            creg = fv * creg + iv * gv;
            float h = ov * tanh_f(creg);
            __hip_atomic_store(&hist[((size_t)t * BATCH + b) * HID + mem * 32 + k],
                               h, __ATOMIC_RELAXED, __HIP_MEMORY_SCOPE_AGENT);
        }
        // release on same wave (wave 0) as the h-stores -> orders them
        if (tid == 0) {
            __hip_atomic_store(&flagsA[P * 8 + mem], t + 1, __ATOMIC_RELEASE,
                               __HIP_MEMORY_SCOPE_AGENT);
        }
    }
}

// ---------------------------------------------------------------------------
// L1 + FC: 256 blocks = mem(16) x group(16). Block (mem,g) serves batches
// 4g..4g+3; owns 64 gate rows: row = gate*256 + mem*16 + k, k<16. Weights
// 64x512 = 32 fp32/thread. Members stride 16 == 0 mod 8 -> same XCD.
// FC: each member already loads full h2[t-1] into vbuf for the recurrence;
// member (mem) exclusively owns (batch mem&3, classes 2*(mem>>2)+{0,1})
// -> plain stores, no atomics, no extra barriers.
// ---------------------------------------------------------------------------
__global__ void lstm_l1_kernel(
    const float* __restrict__ hist, const float* __restrict__ Wih1,
    const float* __restrict__ Whh1, const float* __restrict__ bih1,
    const float* __restrict__ bhh1, const float* __restrict__ Wfc,
    const float* __restrict__ bfc,  const int* __restrict__ lengths,
    float* __restrict__ out, float* __restrict__ xbuf, int* __restrict__ flagsB)
{
    const int g   = blockIdx.x & 15;
    const int mem = blockIdx.x >> 4;       // 0..15
    const int tid = threadIdx.x;
    const int p   = tid >> 6;              // 0..15 col-chunk (32 wide)
    const int r   = tid & 63;              // 0..63 local row
    const int row = (r >> 4) * 256 + mem * 16 + (r & 15);

    float w[32];
#pragma unroll
    for (int q = 0; q < 32; ++q) {
        int col = p * 32 + q;
        w[q] = (col < HID) ? Wih1[row * HID + col] : Whh1[row * HID + (col - HID)];
    }
#pragma unroll
    for (int q = 0; q < 32; ++q) asm volatile("" : "+v"(w[q]));

    float biasv = 0.f;
    if (tid < 256) {
        int rr = tid & 63;
        int row2 = (rr >> 4) * 256 + mem * 16 + (rr & 15);
        biasv = bih1[row2] + bhh1[row2];
    }
    asm volatile("" : "+v"(biasv));
    float creg = 0.f;                      // tid<64: (n=tid>>4, k=tid&15)

    const int nf = mem & 3;                // FC batch (within group)
    const int c0 = (mem >> 2) * 2;         // FC class base
    float wfc = 0.f;
    if (tid < 512) wfc = Wfc[(c0 + (tid >> 8)) * HID + (tid & 255)];
    asm volatile("" : "+v"(wfc));
    const int  lenb = lengths[4 * g + nf];
    float bfcv = (tid < 2) ? bfc[c0 + tid] : 0.f;

    __shared__ __align__(16) float vbuf[2048];  // [n][ h1(256) | h2_prev(256) ]
    __shared__ float pbuf[4096];                // [n][p][r]
    __shared__ float act[256];                  // [n][64]
    __shared__ float fcred[8];

    for (int t = 0; t < SEQ; ++t) {
        if (t > 0 && tid < 16) {
            while (__hip_atomic_load(&flagsB[g * 16 + tid], __ATOMIC_ACQUIRE,
                                     __HIP_MEMORY_SCOPE_AGENT) < t) {}
        }
        __syncthreads();
        {
            int n = tid >> 8, j = tid & 255, b = 4 * g + n;
            vbuf[n * 512 + j] = hist[((size_t)t * BATCH + b) * HID + j];
            float hv = (t == 0) ? 0.f
                : __hip_atomic_load(&xbuf[((size_t)b * 2 + ((t - 1) & 1)) * HID + j],
                                    __ATOMIC_RELAXED, __HIP_MEMORY_SCOPE_AGENT);
            vbuf[n * 512 + HID + j] = hv;
        }
        __syncthreads();

        float a0 = 0.f, a1 = 0.f, a2 = 0.f, a3 = 0.f;
#pragma unroll
        for (int qq = 0; qq < 8; ++qq) {
            float4 v0 = *(const float4*)&vbuf[p * 32 + qq * 4];
            a0 = fmaf(w[qq * 4 + 0], v0.x, a0); a0 = fmaf(w[qq * 4 + 1], v0.y, a0);
            a0 = fmaf(w[qq * 4 + 2], v0.z, a0); a0 = fmaf(w[qq * 4 + 3], v0.w, a0);
            float4 v1 = *(const float4*)&vbuf[512 + p * 32 + qq * 4];
            a1 = fmaf(w[qq * 4 + 0], v1.x, a1); a1 = fmaf(w[qq * 4 + 1], v1.y, a1);
            a1 = fmaf(w[qq * 4 + 2], v1.z, a1); a1 = fmaf(w[qq * 4 + 3], v1.w, a1);
            float4 v2 = *(const float4*)&vbuf[1024 + p * 32 + qq * 4];
            a2 = fmaf(w[qq * 4 + 0], v2.x, a2); a2 = fmaf(w[qq * 4 + 1], v2.y, a2);
            a2 = fmaf(w[qq * 4 + 2], v2.z, a2); a2 = fmaf(w[qq * 4 + 3], v2.w, a2);
            float4 v3 = *(const float4*)&vbuf[1536 + p * 32 + qq * 4];
            a3 = fmaf(w[qq * 4 + 0], v3.x, a3); a3 = fmaf(w[qq * 4 + 1], v3.y, a3);
            a3 = fmaf(w[qq * 4 + 2], v3.z, a3); a3 = fmaf(w[qq * 4 + 3], v3.w, a3);
        }
        pbuf[p * 64 + r]        = a0;
        pbuf[1024 + p * 64 + r] = a1;
        pbuf[2048 + p * 64 + r] = a2;
        pbuf[3072 + p * 64 + r] = a3;

        // FC for step t-1, overlapped before the shared barrier:
        // vbuf h2-half currently holds h2[t-1] (complete, flag-acquired).
        float fval = 0.f;
        if (t > 0 && tid < 512) {
            fval = vbuf[nf * 512 + HID + (tid & 255)] * wfc;
            fval += __shfl_xor(fval, 1);
            fval += __shfl_xor(fval, 2);
            fval += __shfl_xor(fval, 4);
            fval += __shfl_xor(fval, 8);
            fval += __shfl_xor(fval, 16);
            fval += __shfl_xor(fval, 32);
            if ((tid & 63) == 0) fcred[tid >> 6] = fval;
        }
        __syncthreads();

        if (tid < 256) {
            int n = tid >> 6, rw = tid & 63;
            float s = biasv;
#pragma unroll
            for (int q = 0; q < 16; ++q) s += pbuf[n * 1024 + q * 64 + rw];
            act[n * 64 + rw] = ((rw >> 4) == 2) ? tanh_f(s) : sigm(s);
        }
        if (t > 0 && tid < 2 && (t - 1) < lenb) {
            float s2 = fcred[tid * 4 + 0] + fcred[tid * 4 + 1]
                     + fcred[tid * 4 + 2] + fcred[tid * 4 + 3];
            out[((size_t)(4 * g + nf) * SEQ + (t - 1)) * NCLS + c0 + tid] = bfcv + s2;
        }
        __syncthreads();

        if (tid < 64) {
            int n = tid >> 4, k = tid & 15, b = 4 * g + n;
            float iv = act[n * 64 + k],      fv = act[n * 64 + 16 + k];
            float gv = act[n * 64 + 32 + k], ov = act[n * 64 + 48 + k];
            creg = fv * creg + iv * gv;
            float h = ov * tanh_f(creg);
            __hip_atomic_store(&xbuf[((size_t)b * 2 + (t & 1)) * HID + mem * 16 + k],
                               h, __ATOMIC_RELAXED, __HIP_MEMORY_SCOPE_AGENT);
        }
        if (tid == 0) {
            __hip_atomic_store(&flagsB[g * 16 + mem], t + 1, __ATOMIC_RELEASE,
                               __HIP_MEMORY_SCOPE_AGENT);
        }
    }

    // tail: FC for t = SEQ-1 from the final h2
    if (tid < 16) {
        while (__hip_atomic_load(&flagsB[g * 16 + tid], __ATOMIC_ACQUIRE,
                                 __HIP_MEMORY_SCOPE_AGENT) < SEQ) {}
    }
    __syncthreads();
    float fval = 0.f;
    if (tid < 512) {
        int b = 4 * g + nf;
        float hv = __hip_atomic_load(&xbuf[((size_t)b * 2 + ((SEQ - 1) & 1)) * HID + (tid & 255)],
                                     __ATOMIC_RELAXED, __HIP_MEMORY_SCOPE_AGENT);
        fval = hv * wfc;
        fval += __shfl_xor(fval, 1);
        fval += __shfl_xor(fval, 2);
        fval += __shfl_xor(fval, 4);
        fval += __shfl_xor(fval, 8);
        fval += __shfl_xor(fval, 16);
        fval += __shfl_xor(fval, 32);
        if ((tid & 63) == 0) fcred[tid >> 6] = fval;
    }
    __syncthreads();
    if (tid < 2 && (SEQ - 1) < lenb) {
        float s2 = fcred[tid * 4 + 0] + fcred[tid * 4 + 1]
                 + fcred[tid * 4 + 2] + fcred[tid * 4 + 3];
        out[((size_t)(4 * g + nf) * SEQ + (SEQ - 1)) * NCLS + c0 + tid] = bfcv + s2;
    }
}

// ---------------------------------------------------------------------------
extern "C" void kernel_launch(void* const* d_in, const int* in_sizes, int n_in,
                              void* d_out, int out_size, void* d_ws, size_t ws_size,
                              hipStream_t stream) {
    (void)in_sizes; (void)n_in; (void)out_size;
    const float* x     = (const float*)d_in[0];
    const int*   lens  = (const int*)  d_in[1];
    const float* Wih0  = (const float*)d_in[2];
    const float* Whh0  = (const float*)d_in[3];
    const float* bih0  = (const float*)d_in[4];
    const float* bhh0  = (const float*)d_in[5];
    const float* Wih1  = (const float*)d_in[6];
    const float* Whh1  = (const float*)d_in[7];
    const float* bih1  = (const float*)d_in[8];
    const float* bhh1  = (const float*)d_in[9];
    const float* Wfc   = (const float*)d_in[10];
    const float* bfc   = (const float*)d_in[11];
    float* out = (float*)d_out;
    char*  ws  = (char*)d_ws;

    // ws layout: flagsA(1KB) | flagsB(1KB) | xbuf(128KB) | hist(128MiB)
    int*   flagsA = (int*)(ws);
    int*   flagsB = (int*)(ws + 1024);
    float* xbuf   = (float*)(ws + 2048);
    const size_t hist_off = 2048 + (size_t)BATCH * 2 * HID * 4;   // = 133120, 256-aligned
    float* hist = (float*)(ws + hist_off);
    const size_t need = hist_off + (size_t)SEQ * BATCH * HID * 4;
    if (ws_size < need) return;

    hipMemsetAsync(ws, 0, hist_off, stream);  // zero flags + xbuf each launch
    init_out_kernel<<<(BATCH * SEQ * NCLS + 255) / 256, 256, 0, stream>>>(out, bfc);
    lstm_l0_kernel<<<256, 1024, 0, stream>>>(x, Wih0, Whh0, bih0, bhh0, hist, flagsA);
    lstm_l1_kernel<<<256, 1024, 0, stream>>>(hist, Wih1, Whh1, bih1, bhh1, Wfc, bfc,
                                             lens, out, xbuf, flagsB);
}